// Round 1
// baseline (904.563 us; speedup 1.0000x reference)
//
#include <hip/hip_runtime.h>

#define DEV __device__ __forceinline__

constexpr int NXc = 64;   // state dim
constexpr int NUc = 32;   // input dim
constexpr int NHc = 32;   // horizon
constexpr int NBc = 192;  // batch

// workspace layout (float offsets)
constexpr int WS_P    = 0;                          // [NH+1][NX*NX], slots 1..32 used (P_{s+1})
constexpr int WS_QI   = WS_P    + (NHc + 1) * NXc * NXc;  // [NH][NU*NU]  Quu^{-1}
constexpr int WS_QXUT = WS_QI   + NHc * NUc * NUc;        // [NH][NU*NX]  QxuT (rows=u, cols=x)
constexpr int WS_K    = WS_QXUT + NHc * NUc * NXc;        // [NH][NU*NX]  K
constexpr int WS_TOTAL= WS_K    + NHc * NUc * NXc;        // = 299008 floats (~1.2 MB)

DEV float4 ld4(const float* p) { return *reinterpret_cast<const float4*>(p); }
DEV void   st4(float* p, float4 v) { *reinterpret_cast<float4*>(p) = v; }
DEV float  dot4(float4 a, float4 b) {
  return fmaf(a.x, b.x, fmaf(a.y, b.y, fmaf(a.z, b.z, a.w * b.w)));
}
DEV void fma4(float4& a, float s, float4 b) {
  a.x = fmaf(s, b.x, a.x); a.y = fmaf(s, b.y, a.y);
  a.z = fmaf(s, b.z, a.z); a.w = fmaf(s, b.w, a.w);
}
DEV void fma8(float* acc, float s, float4 b0, float4 b1) {
  acc[0] = fmaf(s, b0.x, acc[0]); acc[1] = fmaf(s, b0.y, acc[1]);
  acc[2] = fmaf(s, b0.z, acc[2]); acc[3] = fmaf(s, b0.w, acc[3]);
  acc[4] = fmaf(s, b1.x, acc[4]); acc[5] = fmaf(s, b1.y, acc[5]);
  acc[6] = fmaf(s, b1.z, acc[6]); acc[7] = fmaf(s, b1.w, acc[7]);
}

// ---------------------------------------------------------------------------
// Kernel 1: batch-independent Riccati matrix recursion. 1 block, 256 threads.
// Produces gP[s+1] (P_{s+1}, s=0..31), gQI[s]=Quu_s^{-1}, gQxuT[s], gK[s].
// ---------------------------------------------------------------------------
__global__ __launch_bounds__(256) void k_riccati_mats(
    const float* __restrict__ Ag, const float* __restrict__ Bg,
    const float* __restrict__ Qxg, const float* __restrict__ Rug,
    const float* __restrict__ Qfg, float* __restrict__ ws) {
  __shared__ __align__(16) float sP[NXc * NXc];     // P_{s+1} (symmetric)
  __shared__ __align__(16) float sU[NXc * NXc];     // U = P*A
  __shared__ __align__(16) float sV[NXc * NUc];     // V = P*B
  __shared__ __align__(16) float sQxuT[NUc * NXc];  // QxuT = V^T A  (rows=u, cols=x)
  __shared__ __align__(16) float sK[NUc * NXc];
  __shared__ __align__(16) float sG[2][NUc * NUc];  // GJ ping-pong

  const int t = threadIdx.x;
  float* gP    = ws + WS_P;
  float* gQI   = ws + WS_QI;
  float* gQxuT = ws + WS_QXUT;
  float* gK    = ws + WS_K;

  for (int idx = t; idx < NXc * NXc; idx += 256) sP[idx] = Qfg[idx];
  __syncthreads();

  for (int s = NHc - 1; s >= 0; --s) {
    // store P_{s+1}
    for (int idx = t; idx < NXc * NXc; idx += 256) gP[(s + 1) * NXc * NXc + idx] = sP[idx];

    // V(i,j) = sum_k P[k][i]*B[k][j]   (P symmetric)
    {
      const int i0 = t >> 2;           // 0..63
      const int j0 = (t & 3) * 8;      // 0,8,16,24
      float acc[8] = {0, 0, 0, 0, 0, 0, 0, 0};
#pragma unroll 4
      for (int k = 0; k < NXc; ++k) {
        const float pv = sP[k * NXc + i0];
        fma8(acc, pv, ld4(Bg + k * NUc + j0), ld4(Bg + k * NUc + j0 + 4));
      }
#pragma unroll
      for (int jj = 0; jj < 8; ++jj) sV[i0 * NUc + j0 + jj] = acc[jj];
    }
    __syncthreads();

    // Quu = Ru + B^T V -> sG[0]
    {
      const int i0 = t >> 3, j0 = (t & 7) * 4;
      float4 acc = ld4(Rug + i0 * NUc + j0);
#pragma unroll 4
      for (int k = 0; k < NXc; ++k) {
        fma4(acc, Bg[k * NUc + i0], ld4(sV + k * NUc + j0));
      }
      st4(sG[0] + i0 * NUc + j0, acc);
    }
    // QxuT(i,j) = sum_k A[k][j]*V[k][i]
    {
      const int i0 = t >> 3, j0 = (t & 7) * 8;
      float acc[8] = {0, 0, 0, 0, 0, 0, 0, 0};
#pragma unroll 4
      for (int k = 0; k < NXc; ++k) {
        const float vv = sV[k * NUc + i0];
        fma8(acc, vv, ld4(Ag + k * NXc + j0), ld4(Ag + k * NXc + j0 + 4));
      }
#pragma unroll
      for (int jj = 0; jj < 8; ++jj) sQxuT[i0 * NXc + j0 + jj] = acc[jj];
    }
    // U(i,j) = sum_k P[k][i]*A[k][j]
    {
      const int i0 = (t >> 4) * 4, j0 = (t & 15) * 4;
      float4 acc0 = {0, 0, 0, 0}, acc1 = {0, 0, 0, 0}, acc2 = {0, 0, 0, 0}, acc3 = {0, 0, 0, 0};
#pragma unroll 4
      for (int k = 0; k < NXc; ++k) {
        const float4 p4 = ld4(sP + k * NXc + i0);
        const float4 a4 = ld4(Ag + k * NXc + j0);
        fma4(acc0, p4.x, a4); fma4(acc1, p4.y, a4);
        fma4(acc2, p4.z, a4); fma4(acc3, p4.w, a4);
      }
      st4(sU + (i0 + 0) * NXc + j0, acc0);
      st4(sU + (i0 + 1) * NXc + j0, acc1);
      st4(sU + (i0 + 2) * NXc + j0, acc2);
      st4(sU + (i0 + 3) * NXc + j0, acc3);
    }
    __syncthreads();

    // Gauss-Jordan sweep inverse of Quu (SPD, no pivoting), ping-pong sG[0]<->sG[1]
    {
      const int i = t >> 3;           // row 0..31
      const int k0 = (t & 7) * 4;     // col chunk
      for (int j = 0; j < NUc; ++j) {
        const float* Wa = sG[j & 1];
        float* Wb = sG[(j & 1) ^ 1];
        const float d = Wa[j * NUc + j];
        const float pinv = 1.0f / d;
        const float f = Wa[i * NUc + j];
        const float4 prow = ld4(Wa + j * NUc + k0);
        const float4 own  = ld4(Wa + i * NUc + k0);
        float4 outv;
        if (i == j) {
          outv.x = (k0 + 0 == j) ? pinv : prow.x * pinv;
          outv.y = (k0 + 1 == j) ? pinv : prow.y * pinv;
          outv.z = (k0 + 2 == j) ? pinv : prow.z * pinv;
          outv.w = (k0 + 3 == j) ? pinv : prow.w * pinv;
        } else {
          const float g = f * pinv;
          outv.x = (k0 + 0 == j) ? -g : fmaf(-g, prow.x, own.x);
          outv.y = (k0 + 1 == j) ? -g : fmaf(-g, prow.y, own.y);
          outv.z = (k0 + 2 == j) ? -g : fmaf(-g, prow.z, own.z);
          outv.w = (k0 + 3 == j) ? -g : fmaf(-g, prow.w, own.w);
        }
        st4(Wb + i * NUc + k0, outv);
        __syncthreads();
      }
      // 32 steps (even count) -> result in sG[0]
    }

    // write Quu^{-1}; K = -Qinv * QxuT  (Qinv symmetric)
    {
      for (int idx = t; idx < NUc * NUc; idx += 256) gQI[s * NUc * NUc + idx] = sG[0][idx];
      const int i0 = t >> 3, j0 = (t & 7) * 8;
      float acc[8] = {0, 0, 0, 0, 0, 0, 0, 0};
#pragma unroll 4
      for (int k = 0; k < NUc; ++k) {
        const float qv = sG[0][k * NUc + i0];
        fma8(acc, qv, ld4(sQxuT + k * NXc + j0), ld4(sQxuT + k * NXc + j0 + 4));
      }
#pragma unroll
      for (int jj = 0; jj < 8; ++jj) sK[i0 * NXc + j0 + jj] = -acc[jj];
    }
    __syncthreads();

    // write gK, gQxuT; P' = Qx + A^T U + Qxu*K  (fused, in-place into sP)
    {
      for (int idx = t; idx < NUc * NXc; idx += 256) {
        gK[s * NUc * NXc + idx]    = sK[idx];
        gQxuT[s * NUc * NXc + idx] = sQxuT[idx];
      }
      const int i0 = (t >> 4) * 4, j0 = (t & 15) * 4;
      float4 acc0 = ld4(Qxg + (i0 + 0) * NXc + j0);
      float4 acc1 = ld4(Qxg + (i0 + 1) * NXc + j0);
      float4 acc2 = ld4(Qxg + (i0 + 2) * NXc + j0);
      float4 acc3 = ld4(Qxg + (i0 + 3) * NXc + j0);
#pragma unroll 4
      for (int k = 0; k < NXc; ++k) {
        const float4 a4 = ld4(Ag + k * NXc + i0);   // A[k][i0..3]  (A^T side)
        const float4 u4 = ld4(sU + k * NXc + j0);
        fma4(acc0, a4.x, u4); fma4(acc1, a4.y, u4);
        fma4(acc2, a4.z, u4); fma4(acc3, a4.w, u4);
      }
#pragma unroll 4
      for (int k = 0; k < NUc; ++k) {
        const float4 q4 = ld4(sQxuT + k * NXc + i0); // Qxu[i][k] = QxuT[k][i]
        const float4 k4 = ld4(sK + k * NXc + j0);
        fma4(acc0, q4.x, k4); fma4(acc1, q4.y, k4);
        fma4(acc2, q4.z, k4); fma4(acc3, q4.w, k4);
      }
      st4(sP + (i0 + 0) * NXc + j0, acc0);
      st4(sP + (i0 + 1) * NXc + j0, acc1);
      st4(sP + (i0 + 2) * NXc + j0, acc2);
      st4(sP + (i0 + 3) * NXc + j0, acc3);
    }
    __syncthreads();

    // symmetrize sP (exclusive 4x4-tile pairs)
    {
      const int r = t >> 4, c = t & 15;
      if (r < c) {
#pragma unroll
        for (int a = 0; a < 4; ++a)
#pragma unroll
          for (int bb = 0; bb < 4; ++bb) {
            const int i = r * 4 + a, j = c * 4 + bb;
            const float v = 0.5f * (sP[i * NXc + j] + sP[j * NXc + i]);
            sP[i * NXc + j] = v; sP[j * NXc + i] = v;
          }
      } else if (r == c) {
#pragma unroll
        for (int a = 0; a < 4; ++a)
#pragma unroll
          for (int bb = 0; bb < 4; ++bb)
            if (bb > a) {
              const int i = r * 4 + a, j = c * 4 + bb;
              const float v = 0.5f * (sP[i * NXc + j] + sP[j * NXc + i]);
              sP[i * NXc + j] = v; sP[j * NXc + i] = v;
            }
      }
    }
    __syncthreads();
  }
}

// ---------------------------------------------------------------------------
// Kernel 2: per-batch KKT residuals + backward/forward vector recursion.
// One block per batch element, 256 threads. Output u_new = u + du (1 Newton
// step == converged solution of the affine KKT system).
// ---------------------------------------------------------------------------
__global__ __launch_bounds__(256) void k_solve(
    const float* __restrict__ x0g, const float* __restrict__ xg,
    const float* __restrict__ ug, const float* __restrict__ lg,
    const float* __restrict__ Ag, const float* __restrict__ Bg,
    const float* __restrict__ Qxg, const float* __restrict__ Rug,
    const float* __restrict__ Qfg, const float* __restrict__ ws,
    float* __restrict__ outp) {
  const int b = blockIdx.x;
  const int t = threadIdx.x;

  const float* gP    = ws + WS_P;
  const float* gQI   = ws + WS_QI;
  const float* gQxuT = ws + WS_QXUT;
  const float* gK    = ws + WS_K;

  __shared__ __align__(16) float sx[(NHc + 1) * NXc];   // 2112
  __shared__ __align__(16) float sl[(NHc + 1) * NXc];   // 2112
  __shared__ __align__(16) float su[NHc * NUc];         // 1024
  __shared__ __align__(16) float xres[NHc * NXc];       // 2048
  __shared__ __align__(16) float lxs[NHc * NXc];        // 2048
  __shared__ __align__(16) float lus[NHc * NUc];        // 1024
  __shared__ __align__(16) float kv[NHc * NUc];         // 1024
  __shared__ __align__(16) float sAT[NXc * 65];         // padded A^T: sAT[i*65+k] = A[k][i]
  __shared__ __align__(16) float sp[NXc];
  __shared__ __align__(16) float sw[NXc];
  __shared__ __align__(16) float sqx[NXc];
  __shared__ __align__(16) float squ[NUc];
  __shared__ __align__(16) float sdx[2][NXc];
  __shared__ __align__(16) float sdu[NUc];

  // ---- stage x, lmd, u for this batch element
  for (int idx = t; idx < (NHc + 1) * NXc; idx += 256) {
    const int s = idx >> 6, i = idx & 63;
    sx[idx] = xg[(s * NBc + b) * NXc + i];
    sl[idx] = lg[(s * NBc + b) * NXc + i];
  }
  for (int idx = t; idx < NHc * NUc; idx += 256) {
    const int s = idx >> 5, j = idx & 31;
    su[idx] = ug[(s * NBc + b) * NUc + j];
  }
  // stage padded A^T (conflict-free 65-stride)
  for (int idx = t; idx < NXc * NXc / 4; idx += 256) {
    const int k = idx >> 4;
    const int i = (idx & 15) * 4;
    const float4 a4 = ld4(Ag + k * NXc + i);
    sAT[(i + 0) * 65 + k] = a4.x; sAT[(i + 1) * 65 + k] = a4.y;
    sAT[(i + 2) * 65 + k] = a4.z; sAT[(i + 3) * 65 + k] = a4.w;
  }
  __syncthreads();

  // ---- residuals: xres, lx  (s = t>>3, 8 state outputs each)
  {
    const int s = t >> 3, i0 = (t & 7) * 8;
    float accx[8], accl[8];
#pragma unroll
    for (int ii = 0; ii < 8; ++ii) {
      accx[ii] = -sx[(s + 1) * NXc + i0 + ii];   // - x[s+1]
      accl[ii] = -sl[s * NXc + i0 + ii];         // - lmd[s]
    }
#pragma unroll 2
    for (int k0 = 0; k0 < NXc; k0 += 4) {
      const float4 xv = ld4(sx + s * NXc + k0);
#pragma unroll
      for (int ii = 0; ii < 8; ++ii) {
        accx[ii] += dot4(ld4(Ag + (i0 + ii) * NXc + k0), xv);   // A x[s]
        accl[ii] += dot4(ld4(Qxg + (i0 + ii) * NXc + k0), xv);  // Qx x[s]
      }
    }
#pragma unroll 2
    for (int k0 = 0; k0 < NUc; k0 += 4) {
      const float4 uv = ld4(su + s * NUc + k0);
#pragma unroll
      for (int ii = 0; ii < 8; ++ii)
        accx[ii] += dot4(ld4(Bg + (i0 + ii) * NUc + k0), uv);   // B u[s]
    }
#pragma unroll 4
    for (int k = 0; k < NXc; ++k) {                              // A^T lmd[s+1]
      const float lv = sl[(s + 1) * NXc + k];
      fma8(accl, lv, ld4(Ag + k * NXc + i0), ld4(Ag + k * NXc + i0 + 4));
    }
#pragma unroll
    for (int ii = 0; ii < 8; ++ii) {
      xres[s * NXc + i0 + ii] = accx[ii];
      lxs[s * NXc + i0 + ii] = accl[ii];
    }
  }
  // ---- residual lu  (s = t>>3, 4 input outputs each)
  {
    const int s = t >> 3, j0 = (t & 7) * 4;
    float4 acc = {0, 0, 0, 0};
#pragma unroll 2
    for (int k0 = 0; k0 < NUc; k0 += 4) {
      const float4 uv = ld4(su + s * NUc + k0);
      acc.x += dot4(ld4(Rug + (j0 + 0) * NUc + k0), uv);
      acc.y += dot4(ld4(Rug + (j0 + 1) * NUc + k0), uv);
      acc.z += dot4(ld4(Rug + (j0 + 2) * NUc + k0), uv);
      acc.w += dot4(ld4(Rug + (j0 + 3) * NUc + k0), uv);
    }
#pragma unroll 4
    for (int k = 0; k < NXc; ++k) {                              // B^T lmd[s+1]
      const float lv = sl[(s + 1) * NXc + k];
      fma4(acc, lv, ld4(Bg + k * NUc + j0));
    }
    lus[s * NUc + j0 + 0] = acc.x; lus[s * NUc + j0 + 1] = acc.y;
    lus[s * NUc + j0 + 2] = acc.z; lus[s * NUc + j0 + 3] = acc.w;
  }
  // ---- p_N = lxN = Qf x[N] - lmd[N];  dx_0 = -(x[0]-x0)
  if (t < NXc) {
    float acc = -sl[NHc * NXc + t];
#pragma unroll 4
    for (int k0 = 0; k0 < NXc; k0 += 4)
      acc += dot4(ld4(Qfg + t * NXc + k0), ld4(sx + NHc * NXc + k0));
    sp[t] = acc;
  } else if (t < 2 * NXc) {
    const int i = t - NXc;
    sdx[0][i] = x0g[b * NXc + i] - sx[i];
  }
  __syncthreads();

  // ---- backward vector recursion
  for (int s = NHc - 1; s >= 0; --s) {
    const float* Ps1 = gP + (s + 1) * NXc * NXc;
    {  // w = P_{s+1} xres[s] + p
      const int i = t >> 2, p = t & 3, k0 = p * 16;
      float acc = 0;
#pragma unroll
      for (int kk = 0; kk < 16; kk += 4)
        acc += dot4(ld4(Ps1 + i * NXc + k0 + kk), ld4(xres + s * NXc + k0 + kk));
      acc += __shfl_xor(acc, 1); acc += __shfl_xor(acc, 2);
      if (p == 0) sw[i] = acc + sp[i];
    }
    __syncthreads();
    {  // qx = lx[s] + A^T w
      const int i = t >> 2, p = t & 3, k0 = p * 16;
      float acc = 0;
#pragma unroll
      for (int kk = 0; kk < 16; ++kk) acc += sAT[i * 65 + k0 + kk] * sw[k0 + kk];
      acc += __shfl_xor(acc, 1); acc += __shfl_xor(acc, 2);
      if (p == 0) sqx[i] = lxs[s * NXc + i] + acc;
    }
    if (t < 128) {  // qu = lu[s] + B^T w
      const int j = t >> 2, p = t & 3, k0 = p * 16;
      float acc = 0;
#pragma unroll
      for (int kk = 0; kk < 16; ++kk) acc += Bg[(k0 + kk) * NUc + j] * sw[k0 + kk];
      acc += __shfl_xor(acc, 1); acc += __shfl_xor(acc, 2);
      if (p == 0) squ[j] = lus[s * NUc + j] + acc;
    }
    __syncthreads();
    {  // k_s = -Quu^{-1} qu
      const int o = t >> 3, p = t & 7, k0 = p * 4;
      float acc = dot4(ld4(gQI + s * NUc * NUc + o * NUc + k0), ld4(squ + k0));
      acc += __shfl_xor(acc, 1); acc += __shfl_xor(acc, 2); acc += __shfl_xor(acc, 4);
      if (p == 0) kv[s * NUc + o] = -acc;
    }
    __syncthreads();
    {  // p = qx + Qxu k_s   (Qxu[i][k] = QxuT[k][i])
      const int i = t >> 2, p = t & 3, k0 = p * 8;
      float acc = 0;
#pragma unroll
      for (int kk = 0; kk < 8; ++kk)
        acc += gQxuT[s * NUc * NXc + (k0 + kk) * NXc + i] * kv[s * NUc + k0 + kk];
      acc += __shfl_xor(acc, 1); acc += __shfl_xor(acc, 2);
      if (p == 0) sp[i] = sqx[i] + acc;
    }
    __syncthreads();
  }

  // ---- forward rollout, write u + du
  for (int s = 0; s < NHc; ++s) {
    const int cur = s & 1, nxt = cur ^ 1;
    {  // du = K dx + k ; out = u + du
      const int o = t >> 3, p = t & 7, k0 = p * 8;
      const float* Krow = gK + s * NUc * NXc + o * NXc;
      float acc = dot4(ld4(Krow + k0), ld4(&sdx[cur][k0]))
                + dot4(ld4(Krow + k0 + 4), ld4(&sdx[cur][k0 + 4]));
      acc += __shfl_xor(acc, 1); acc += __shfl_xor(acc, 2); acc += __shfl_xor(acc, 4);
      if (p == 0) {
        const float du = acc + kv[s * NUc + o];
        sdu[o] = du;
        const int gi = (s * NBc + b) * NUc + o;
        outp[gi] = ug[gi] + du;
      }
    }
    __syncthreads();
    {  // dx' = A dx + B du + xres[s]
      const int i = t >> 2, p = t & 3;
      const int ka = p * 16, kb = p * 8;
      float acc = 0;
#pragma unroll
      for (int kk = 0; kk < 16; kk += 4)
        acc += dot4(ld4(Ag + i * NXc + ka + kk), ld4(&sdx[cur][ka + kk]));
      acc += dot4(ld4(Bg + i * NUc + kb), ld4(sdu + kb));
      acc += dot4(ld4(Bg + i * NUc + kb + 4), ld4(sdu + kb + 4));
      acc += __shfl_xor(acc, 1); acc += __shfl_xor(acc, 2);
      if (p == 0) sdx[nxt][i] = acc + xres[s * NXc + i];
    }
    __syncthreads();
  }
}

extern "C" void kernel_launch(void* const* d_in, const int* in_sizes, int n_in,
                              void* d_out, int out_size, void* d_ws, size_t ws_size,
                              hipStream_t stream) {
  const float* x0  = (const float*)d_in[0];
  const float* x   = (const float*)d_in[1];
  const float* u   = (const float*)d_in[2];
  const float* lmd = (const float*)d_in[3];
  const float* A   = (const float*)d_in[4];
  const float* Bm  = (const float*)d_in[5];
  const float* Qx  = (const float*)d_in[6];
  const float* Ru  = (const float*)d_in[7];
  const float* Qf  = (const float*)d_in[8];
  float* ws  = (float*)d_ws;
  float* out = (float*)d_out;

  hipLaunchKernelGGL(k_riccati_mats, dim3(1), dim3(256), 0, stream,
                     A, Bm, Qx, Ru, Qf, ws);
  hipLaunchKernelGGL(k_solve, dim3(NBc), dim3(256), 0, stream,
                     x0, x, u, lmd, A, Bm, Qx, Ru, Qf, ws, out);
}

// Round 2
// 798.922 us; speedup vs baseline: 1.1322x; 1.1322x over previous
//
#include <hip/hip_runtime.h>

#define DEV __device__ __forceinline__

constexpr int NX = 64;   // state dim
constexpr int NU = 32;   // input dim
constexpr int NH = 32;   // horizon
constexpr int NB = 192;  // batch
constexpr int SX = 68;   // padded LDS stride for 64-col matrices
constexpr int SU = 36;   // padded LDS stride for 32-col matrices

// workspace layout (float offsets)
constexpr int WS_P   = 0;                         // [NH+1][64*64]  P_{s}
constexpr int WS_QI  = WS_P  + (NH + 1) * NX * NX; // [NH][32*32]   Quu^{-1} row-major
constexpr int WS_QXU = WS_QI + NH * NU * NU;       // [NH][64*32]   Qxu row-major (x,u)
constexpr int WS_K   = WS_QXU + NH * NX * NU;      // [NH][32*64]   K row-major (u,x)

DEV float4 ld4(const float* p) { return *reinterpret_cast<const float4*>(p); }
DEV void   st4(float* p, float4 v) { *reinterpret_cast<float4*>(p) = v; }
DEV float  dot4(float4 a, float4 b) {
  return fmaf(a.x, b.x, fmaf(a.y, b.y, fmaf(a.z, b.z, a.w * b.w)));
}
DEV void fma4(float4& a, float s, float4 b) {
  a.x = fmaf(s, b.x, a.x); a.y = fmaf(s, b.y, a.y);
  a.z = fmaf(s, b.z, a.z); a.w = fmaf(s, b.w, a.w);
}
DEV void fma8(float* acc, float s, float4 b0, float4 b1) {
  acc[0] = fmaf(s, b0.x, acc[0]); acc[1] = fmaf(s, b0.y, acc[1]);
  acc[2] = fmaf(s, b0.z, acc[2]); acc[3] = fmaf(s, b0.w, acc[3]);
  acc[4] = fmaf(s, b1.x, acc[4]); acc[5] = fmaf(s, b1.y, acc[5]);
  acc[6] = fmaf(s, b1.z, acc[6]); acc[7] = fmaf(s, b1.w, acc[7]);
}

// ---------------------------------------------------------------------------
// Kernel 1: batch-independent Riccati matrix recursion. 1 block, 512 threads.
// LDS exactly 64 KB. GJ inverse = wave-0 register sweep (no barriers),
// overlapped with waves 1-7 computing P'a = Qx + A^T U.
// ---------------------------------------------------------------------------
__global__ __launch_bounds__(512) void k_riccati_mats(
    const float* __restrict__ Ag, const float* __restrict__ Bg,
    const float* __restrict__ Qxg, const float* __restrict__ Rug,
    const float* __restrict__ Qfg, float* __restrict__ ws) {
  __shared__ __align__(16) float sP[NX * SX];     // 17408 B  P_{s+1}, then P'
  __shared__ __align__(16) float sU[NX * SX];     // 17408 B  U = P*A; later K (32*SX)
  __shared__ __align__(16) float sV[NX * SU];     //  9216 B  V = P*B
  __shared__ __align__(16) float sQxuT[NU * SX];  //  8704 B  QxuT (u,x)
  __shared__ __align__(16) float sQ[NU * SU];     //  4608 B  Quu, then Quu^{-1}
  __shared__ __align__(16) float sB[NX * NU];     //  8192 B  B staged (unpadded)
  // total = 65536 B exactly

  const int t = threadIdx.x;
  float* gP   = ws + WS_P;
  float* gQI  = ws + WS_QI;
  float* gQxu = ws + WS_QXU;
  float* gK   = ws + WS_K;
  float* sK   = sU;  // alias: K written in Ph4, U dead after Ph3

  // stage sP = Qf, sB = B
  for (int idx = t; idx < NX * NX / 4; idx += 512) {
    const int i = idx >> 4, j0 = (idx & 15) * 4;
    st4(sP + i * SX + j0, ld4(Qfg + i * NX + j0));
  }
  for (int idx = t; idx < NX * NU / 4; idx += 512) {
    const int i = idx >> 3, j0 = (idx & 7) * 4;
    st4(sB + i * NU + j0, ld4(Bg + i * NU + j0));
  }
  __syncthreads();

  for (int s = NH - 1; s >= 0; --s) {
    // ---- gP store (P_{s+1}) + Ph1: U = P*A, V = P*B (one pass over P rows)
    {
      for (int idx = t; idx < NX * NX / 4; idx += 512) {
        const int i = idx >> 4, j0 = (idx & 15) * 4;
        st4(gP + (s + 1) * NX * NX + i * NX + j0, ld4(sP + i * SX + j0));
      }
      const int i0 = t >> 3, j0u = (t & 7) * 8, j0v = (t & 7) * 4;
      float accU[8] = {0, 0, 0, 0, 0, 0, 0, 0};
      float4 accV = {0, 0, 0, 0};
#pragma unroll 4
      for (int k = 0; k < NX; ++k) {
        const float pv = sP[i0 * SX + k];   // P[i0][k] (symmetric)
        fma8(accU, pv, ld4(Ag + k * NX + j0u), ld4(Ag + k * NX + j0u + 4));
        fma4(accV, pv, ld4(sB + k * NU + j0v));
      }
#pragma unroll
      for (int jj = 0; jj < 8; ++jj) sU[i0 * SX + j0u + jj] = accU[jj];
      st4(sV + i0 * SU + j0v, accV);
    }
    __syncthreads();

    // ---- Ph2: Quu = Ru + B^T V (t<256) ; QxuT = B^T U (t>=256)
    if (t < 256) {
      const int i0 = t >> 3, j0 = (t & 7) * 4;
      float4 acc = ld4(Rug + i0 * NU + j0);
#pragma unroll 4
      for (int k = 0; k < NX; ++k)
        fma4(acc, sB[k * NU + i0], ld4(sV + k * SU + j0));
      st4(sQ + i0 * SU + j0, acc);
    } else {
      const int u0 = (t & 255) >> 3, x0 = (t & 7) * 8;
      float acc[8] = {0, 0, 0, 0, 0, 0, 0, 0};
#pragma unroll 4
      for (int k = 0; k < NX; ++k)
        fma8(acc, sB[k * NU + u0], ld4(sU + k * SX + x0), ld4(sU + k * SX + x0 + 4));
#pragma unroll
      for (int jj = 0; jj < 8; ++jj) sQxuT[u0 * SX + x0 + jj] = acc[jj];
    }
    __syncthreads();

    // ---- Ph3: wave 0: register GJ inverse of Quu ; waves 1-7: P'a = Qx + A^T U
    if (t < 64) {
      const int i = t & 31, h = t >> 5;   // row, col-half
      float W[16];
#pragma unroll
      for (int r = 0; r < 16; ++r) W[r] = sQ[i * SU + h * 16 + r];
#pragma unroll
      for (int j = 0; j < NU; ++j) {
        const int jh = j >> 4, jr = j & 15;
        const float d = __shfl(W[jr], j | (jh << 5));
        const float pinv = 1.0f / d;
        const float f = __shfl(W[jr], i | (jh << 5));
        float pr[16];
#pragma unroll
        for (int r = 0; r < 16; ++r) pr[r] = __shfl(W[r], j | (h << 5));
        float nw[16];
        if (i == j) {
#pragma unroll
          for (int r = 0; r < 16; ++r) nw[r] = pr[r] * pinv;
          if (h == jh) nw[jr] = pinv;
        } else {
          const float g = f * pinv;
#pragma unroll
          for (int r = 0; r < 16; ++r) nw[r] = fmaf(-g, pr[r], W[r]);
          if (h == jh) nw[jr] = -g;
        }
#pragma unroll
        for (int r = 0; r < 16; ++r) W[r] = nw[r];
      }
#pragma unroll
      for (int r = 0; r < 16; ++r) {
        sQ[i * SU + h * 16 + r] = W[r];
        gQI[s * NU * NU + i * NU + h * 16 + r] = W[r];
      }
    } else {
      const int tt = t - 64;
      const int j0 = (tt & 7) * 8;
      for (int i0 = tt >> 3; i0 < NX; i0 += 56) {
        float acc[8];
        const float4 q0 = ld4(Qxg + i0 * NX + j0), q1 = ld4(Qxg + i0 * NX + j0 + 4);
        acc[0] = q0.x; acc[1] = q0.y; acc[2] = q0.z; acc[3] = q0.w;
        acc[4] = q1.x; acc[5] = q1.y; acc[6] = q1.z; acc[7] = q1.w;
#pragma unroll 4
        for (int k = 0; k < NX; ++k)
          fma8(acc, Ag[k * NX + i0], ld4(sU + k * SX + j0), ld4(sU + k * SX + j0 + 4));
#pragma unroll
        for (int jj = 0; jj < 8; ++jj) sP[i0 * SX + j0 + jj] = acc[jj];
      }
    }
    __syncthreads();

    // ---- Ph4: K = -Qinv * QxuT -> sK (alias sU) + gK ; gQxu transpose-store
    {
      const int u0 = t >> 4, x0 = (t & 15) * 4;
      float4 acc = {0, 0, 0, 0};
#pragma unroll 4
      for (int m = 0; m < NU; ++m)
        fma4(acc, sQ[u0 * SU + m], ld4(sQxuT + m * SX + x0));
      acc.x = -acc.x; acc.y = -acc.y; acc.z = -acc.z; acc.w = -acc.w;
      st4(sK + u0 * SX + x0, acc);
      st4(gK + s * NU * NX + u0 * NX + x0, acc);
    }
    {
      const int i = t >> 3, m0 = (t & 7) * 4;
      float4 v;
      v.x = sQxuT[(m0 + 0) * SX + i];
      v.y = sQxuT[(m0 + 1) * SX + i];
      v.z = sQxuT[(m0 + 2) * SX + i];
      v.w = sQxuT[(m0 + 3) * SX + i];
      st4(gQxu + s * NX * NU + i * NU + m0, v);
    }
    __syncthreads();

    // ---- Ph5: sP += Qxu * K   (Qxu(i,m) = QxuT(m,i))
    {
      const int i0 = t >> 3, j0 = (t & 7) * 8;
      float acc[8];
      const float4 p0 = ld4(sP + i0 * SX + j0), p1 = ld4(sP + i0 * SX + j0 + 4);
      acc[0] = p0.x; acc[1] = p0.y; acc[2] = p0.z; acc[3] = p0.w;
      acc[4] = p1.x; acc[5] = p1.y; acc[6] = p1.z; acc[7] = p1.w;
#pragma unroll 4
      for (int m = 0; m < NU; ++m)
        fma8(acc, sQxuT[m * SX + i0], ld4(sK + m * SX + j0), ld4(sK + m * SX + j0 + 4));
#pragma unroll
      for (int jj = 0; jj < 8; ++jj) sP[i0 * SX + j0 + jj] = acc[jj];
    }
    __syncthreads();

    // ---- Ph6: symmetrize sP in place
    if (t < 256) {
      const int r = t >> 4, c = t & 15;
      if (r < c) {
#pragma unroll
        for (int a = 0; a < 4; ++a)
#pragma unroll
          for (int bb = 0; bb < 4; ++bb) {
            const int i = r * 4 + a, j = c * 4 + bb;
            const float v = 0.5f * (sP[i * SX + j] + sP[j * SX + i]);
            sP[i * SX + j] = v; sP[j * SX + i] = v;
          }
      } else if (r == c) {
#pragma unroll
        for (int a = 0; a < 4; ++a)
#pragma unroll
          for (int bb = 0; bb < 4; ++bb)
            if (bb > a) {
              const int i = r * 4 + a, j = c * 4 + bb;
              const float v = 0.5f * (sP[i * SX + j] + sP[j * SX + i]);
              sP[i * SX + j] = v; sP[j * SX + i] = v;
            }
      }
    }
    __syncthreads();
  }
}

// ---------------------------------------------------------------------------
// Kernel 2: per-batch KKT residuals (256 thr, parallel) + wave-0-only
// backward/forward recursion (no barriers, wave-synchronous LDS).
// ---------------------------------------------------------------------------
__global__ __launch_bounds__(256) void k_solve(
    const float* __restrict__ x0g, const float* __restrict__ xg,
    const float* __restrict__ ug, const float* __restrict__ lg,
    const float* __restrict__ Ag, const float* __restrict__ Bg,
    const float* __restrict__ Qxg, const float* __restrict__ Rug,
    const float* __restrict__ Qfg, const float* __restrict__ ws,
    float* __restrict__ outp) {
  const int b = blockIdx.x;
  const int t = threadIdx.x;

  const float* gP   = ws + WS_P;
  const float* gQI  = ws + WS_QI;
  const float* gQxu = ws + WS_QXU;
  const float* gK   = ws + WS_K;

  __shared__ __align__(16) float buf[11584];   // 46336 B
  float* sx   = buf;            // 2112  [0,2112)     (dead after residuals)
  float* sl   = buf + 2112;     // 2112  [2112,4224)  (dead after residuals)
  float* su   = buf + 4224;     // 1024  [4224,5248)  (dead after residuals)
  float* sAT  = buf;            // overlay: 64*68 = 4352  A^T padded, staged late
  float* xres = buf + 5248;     // 2048
  float* lxs  = buf + 7296;     // 2048
  float* lus  = buf + 9344;     // 1024
  float* kv   = buf + 10368;    // 1024
  float* swv  = buf + 11392;    // 64
  float* sqv  = buf + 11456;    // 32
  float* sduv = buf + 11488;    // 32
  float* sdxv = buf + 11520;    // 64

  // ---- stage x, lmd, u for this batch element
  for (int idx = t; idx < (NH + 1) * NX; idx += 256) {
    const int s = idx >> 6, i = idx & 63;
    sx[idx] = xg[(s * NB + b) * NX + i];
    sl[idx] = lg[(s * NB + b) * NX + i];
  }
  for (int idx = t; idx < NH * NU; idx += 256) {
    const int s = idx >> 5, j = idx & 31;
    su[idx] = ug[(s * NB + b) * NU + j];
  }
  __syncthreads();

  // ---- residuals: xres, lx  (s = t>>3, 8 state outputs each)
  {
    const int s = t >> 3, i0 = (t & 7) * 8;
    float accx[8], accl[8];
#pragma unroll
    for (int ii = 0; ii < 8; ++ii) {
      accx[ii] = -sx[(s + 1) * NX + i0 + ii];
      accl[ii] = -sl[s * NX + i0 + ii];
    }
#pragma unroll 2
    for (int k0 = 0; k0 < NX; k0 += 4) {
      const float4 xv = ld4(sx + s * NX + k0);
#pragma unroll
      for (int ii = 0; ii < 8; ++ii) {
        accx[ii] += dot4(ld4(Ag + (i0 + ii) * NX + k0), xv);
        accl[ii] += dot4(ld4(Qxg + (i0 + ii) * NX + k0), xv);
      }
    }
#pragma unroll 2
    for (int k0 = 0; k0 < NU; k0 += 4) {
      const float4 uv = ld4(su + s * NU + k0);
#pragma unroll
      for (int ii = 0; ii < 8; ++ii)
        accx[ii] += dot4(ld4(Bg + (i0 + ii) * NU + k0), uv);
    }
#pragma unroll 4
    for (int k = 0; k < NX; ++k) {
      const float lv = sl[(s + 1) * NX + k];
      fma8(accl, lv, ld4(Ag + k * NX + i0), ld4(Ag + k * NX + i0 + 4));
    }
#pragma unroll
    for (int ii = 0; ii < 8; ++ii) {
      xres[s * NX + i0 + ii] = accx[ii];
      lxs[s * NX + i0 + ii] = accl[ii];
    }
  }
  // ---- residual lu
  {
    const int s = t >> 3, j0 = (t & 7) * 4;
    float4 acc = {0, 0, 0, 0};
#pragma unroll 2
    for (int k0 = 0; k0 < NU; k0 += 4) {
      const float4 uv = ld4(su + s * NU + k0);
      acc.x += dot4(ld4(Rug + (j0 + 0) * NU + k0), uv);
      acc.y += dot4(ld4(Rug + (j0 + 1) * NU + k0), uv);
      acc.z += dot4(ld4(Rug + (j0 + 2) * NU + k0), uv);
      acc.w += dot4(ld4(Rug + (j0 + 3) * NU + k0), uv);
    }
#pragma unroll 4
    for (int k = 0; k < NX; ++k) {
      const float lv = sl[(s + 1) * NX + k];
      fma4(acc, lv, ld4(Bg + k * NU + j0));
    }
    lus[s * NU + j0 + 0] = acc.x; lus[s * NU + j0 + 1] = acc.y;
    lus[s * NU + j0 + 2] = acc.z; lus[s * NU + j0 + 3] = acc.w;
  }
  __syncthreads();

  // ---- wave 0: p_N = Qf x[N] - lmd[N] ; dx0 = x0 - x[0]   (registers)
  float p_i = 0.0f, dx_i = 0.0f;
  if (t < 64) {
    const int i = t;
    float acc = -sl[NH * NX + i];
#pragma unroll 4
    for (int k0 = 0; k0 < NX; k0 += 4)
      acc += dot4(ld4(Qfg + i * NX + k0), ld4(sx + NH * NX + k0));
    p_i = acc;
    dx_i = x0g[b * NX + i] - sx[i];
  }
  __syncthreads();

  // ---- overlay staging of A^T (padded 68) into dead sx/sl region
  for (int idx = t; idx < NX * NX / 4; idx += 256) {
    const int k = idx >> 4, i4 = (idx & 15) * 4;
    const float4 a4 = ld4(Ag + k * NX + i4);
    sAT[(i4 + 0) * SX + k] = a4.x;
    sAT[(i4 + 1) * SX + k] = a4.y;
    sAT[(i4 + 2) * SX + k] = a4.z;
    sAT[(i4 + 3) * SX + k] = a4.w;
  }
  __syncthreads();

  if (t >= 64) return;          // waves 1-3 done; wave 0 continues barrier-free

  const int i = t;              // state row owned by this lane
  const int j = t & 31;         // input row owned by this lane
  const int hh = t >> 5;        // half (for 32-split reductions)

  // ---- backward recursion (wave-synchronous)
  for (int s = NH - 1; s >= 0; --s) {
    // w = P_{s+1} xres_s + p   (lane i computes full row dot)
    const float* Pr = gP + (s + 1) * NX * NX + i * NX;
    const float* xr = xres + s * NX;
    float w = p_i;
#pragma unroll
    for (int k0 = 0; k0 < NX; k0 += 16) {
      w += dot4(ld4(Pr + k0),      ld4(xr + k0));
      w += dot4(ld4(Pr + k0 + 4),  ld4(xr + k0 + 4));
      w += dot4(ld4(Pr + k0 + 8),  ld4(xr + k0 + 8));
      w += dot4(ld4(Pr + k0 + 12), ld4(xr + k0 + 12));
    }
    swv[i] = w;

    // qx = lx + A^T w  (keep in register)
    float qx = lxs[s * NX + i];
#pragma unroll
    for (int k0 = 0; k0 < NX; k0 += 16) {
      qx += dot4(ld4(sAT + i * SX + k0),      ld4(swv + k0));
      qx += dot4(ld4(sAT + i * SX + k0 + 4),  ld4(swv + k0 + 4));
      qx += dot4(ld4(sAT + i * SX + k0 + 8),  ld4(swv + k0 + 8));
      qx += dot4(ld4(sAT + i * SX + k0 + 12), ld4(swv + k0 + 12));
    }

    // qu = lu + B^T w  (half-split over k, combine across halves)
    float qa = 0.0f;
    const int kb = hh * 32;
#pragma unroll 8
    for (int kk = 0; kk < 32; ++kk)
      qa = fmaf(Bg[(kb + kk) * NU + j], swv[kb + kk], qa);
    qa += __shfl_xor(qa, 32);
    const float qu = qa + lus[s * NU + j];
    if (hh == 0) sqv[j] = qu;

    // k_s = -Quu^{-1} qu  (half-split over m)
    const float* Qr = gQI + s * NU * NU + j * NU + hh * 16;
    float ka = dot4(ld4(Qr),      ld4(sqv + hh * 16))
             + dot4(ld4(Qr + 4),  ld4(sqv + hh * 16 + 4))
             + dot4(ld4(Qr + 8),  ld4(sqv + hh * 16 + 8))
             + dot4(ld4(Qr + 12), ld4(sqv + hh * 16 + 12));
    ka += __shfl_xor(ka, 32);
    if (hh == 0) kv[s * NU + j] = -ka;

    // p = qx + Qxu k_s  (lane i reads gQxu row i)
    const float* Xr = gQxu + s * NX * NU + i * NU;
    float pp = qx;
#pragma unroll
    for (int m0 = 0; m0 < NU; m0 += 4)
      pp += dot4(ld4(Xr + m0), ld4(kv + s * NU + m0));
    p_i = pp;
  }

  // ---- forward rollout (wave-synchronous), write u + du
  sdxv[i] = dx_i;
  for (int s = 0; s < NH; ++s) {
    // du = K dx + k   (half-split over k)
    const float* Kr = gK + s * NU * NX + j * NX + hh * 32;
    const float* dxh = sdxv + hh * 32;
    float da = 0.0f;
#pragma unroll
    for (int k0 = 0; k0 < 32; k0 += 16) {
      da += dot4(ld4(Kr + k0),      ld4(dxh + k0));
      da += dot4(ld4(Kr + k0 + 4),  ld4(dxh + k0 + 4));
      da += dot4(ld4(Kr + k0 + 8),  ld4(dxh + k0 + 8));
      da += dot4(ld4(Kr + k0 + 12), ld4(dxh + k0 + 12));
    }
    da += __shfl_xor(da, 32);
    const float du = da + kv[s * NU + j];
    if (hh == 0) {
      const int gi = (s * NB + b) * NU + j;
      outp[gi] = ug[gi] + du;
      sduv[j] = du;
    }

    // dx' = A dx + B du + xres  (lane i full row dots; reads before write, in-order)
    float nxv = xres[s * NX + i];
    const float* Ar = Ag + i * NX;
#pragma unroll
    for (int k0 = 0; k0 < NX; k0 += 4)
      nxv += dot4(ld4(Ar + k0), ld4(sdxv + k0));
    const float* Br = Bg + i * NU;
#pragma unroll
    for (int m0 = 0; m0 < NU; m0 += 4)
      nxv += dot4(ld4(Br + m0), ld4(sduv + m0));
    sdxv[i] = nxv;
  }
}

extern "C" void kernel_launch(void* const* d_in, const int* in_sizes, int n_in,
                              void* d_out, int out_size, void* d_ws, size_t ws_size,
                              hipStream_t stream) {
  const float* x0  = (const float*)d_in[0];
  const float* x   = (const float*)d_in[1];
  const float* u   = (const float*)d_in[2];
  const float* lmd = (const float*)d_in[3];
  const float* A   = (const float*)d_in[4];
  const float* Bm  = (const float*)d_in[5];
  const float* Qx  = (const float*)d_in[6];
  const float* Ru  = (const float*)d_in[7];
  const float* Qf  = (const float*)d_in[8];
  float* ws  = (float*)d_ws;
  float* out = (float*)d_out;

  hipLaunchKernelGGL(k_riccati_mats, dim3(1), dim3(512), 0, stream,
                     A, Bm, Qx, Ru, Qf, ws);
  hipLaunchKernelGGL(k_solve, dim3(NB), dim3(256), 0, stream,
                     x0, x, u, lmd, A, Bm, Qx, Ru, Qf, ws, out);
}